// Round 3
// baseline (607.497 us; speedup 1.0000x reference)
//
#include <hip/hip_runtime.h>
#include <cstdint>
#include <cstddef>

#define D_MODEL 2048
#define SEQ     2048
#define NB      2
#define ROWS    4096      // NB*SEQ
#define QKV_N   3072      // 2048 + 2*4*128
#define NH      16
#define NKV     4
#define HD      128
#define EPSV    1e-5f
// 1/sqrt(128) * log2(e): folded into Q at RoPE time -> scores arrive in log2 domain
#define QPRE    (0.08838834764831845f * 1.4426950408889634f)

typedef unsigned short ushort_t;
typedef __attribute__((ext_vector_type(8))) short  short8;
typedef __attribute__((ext_vector_type(4))) short  short4v;
typedef __attribute__((ext_vector_type(4))) float  floatx4;

__device__ __forceinline__ ushort_t f2b(float f) {
    unsigned u = __float_as_uint(f);
    u += 0x7fffu + ((u >> 16) & 1u);   // RNE bf16
    return (ushort_t)(u >> 16);
}
__device__ __forceinline__ float b2f(ushort_t u) {
    return __uint_as_float(((unsigned)u) << 16);
}

// pack two f32 -> bf16 pair (round-half-up via +0x8000, then byte-perm)
__device__ __forceinline__ unsigned pkbf(float lo, float hi) {
    unsigned u0 = __float_as_uint(lo) + 0x8000u;
    unsigned u1 = __float_as_uint(hi) + 0x8000u;
    return __builtin_amdgcn_perm(u1, u0, 0x07060302u);
}

#if __has_builtin(__builtin_amdgcn_mfma_f32_16x16x16bf16_1k)
#define HAVE_1K 1
#endif

__device__ __forceinline__ floatx4 pv_mfma(short4v a, short4v b, floatx4 c) {
#ifdef HAVE_1K
    return __builtin_amdgcn_mfma_f32_16x16x16bf16_1k(a, b, c, 0, 0, 0);
#else
    // emulate 16x16x16 with zero-padded 16x16x32: k slot q4*8+j (j<4) <-> kv q4*4+j
    short8 a8 = {a[0], a[1], a[2], a[3], 0, 0, 0, 0};
    short8 b8 = {b[0], b[1], b[2], b[3], 0, 0, 0, 0};
    return __builtin_amdgcn_mfma_f32_16x16x32_bf16(a8, b8, c, 0, 0, 0);
#endif
}

#define GLD_LDS16(gp, lp) __builtin_amdgcn_global_load_lds( \
    (const __attribute__((address_space(1))) void*)(gp),   \
    (__attribute__((address_space(3))) void*)(lp), 16, 0, 0)

// ---------------- RMSNorm (fp32 in) -> bf16 out -----------------------------
__global__ __launch_bounds__(256) void k_rmsnorm_bf16(
        const float* __restrict__ x, const float* __restrict__ w,
        ushort_t* __restrict__ out) {
    int row = blockIdx.x, t = threadIdx.x;
    const float4* xr = (const float4*)(x + (size_t)row * D_MODEL);
    float4 a = xr[t], b = xr[t + 256];
    float ss = a.x*a.x + a.y*a.y + a.z*a.z + a.w*a.w
             + b.x*b.x + b.y*b.y + b.z*b.z + b.w*b.w;
    for (int m = 1; m < 64; m <<= 1) ss += __shfl_xor(ss, m);
    __shared__ float sred[4];
    if ((t & 63) == 0) sred[t >> 6] = ss;
    __syncthreads();
    float r = rsqrtf((sred[0] + sred[1] + sred[2] + sred[3]) * (1.0f / D_MODEL) + EPSV);
    const float4* wr = (const float4*)w;
    float4 wa = wr[t], wb = wr[t + 256];
    ushort4 pa, pb;
    pa.x = f2b(a.x * r * wa.x); pa.y = f2b(a.y * r * wa.y);
    pa.z = f2b(a.z * r * wa.z); pa.w = f2b(a.w * r * wa.w);
    pb.x = f2b(b.x * r * wb.x); pb.y = f2b(b.y * r * wb.y);
    pb.z = f2b(b.z * r * wb.z); pb.w = f2b(b.w * r * wb.w);
    ushort4* o = (ushort4*)(out + (size_t)row * D_MODEL);
    o[t] = pa; o[t + 256] = pb;
}

// ---------------- RMSNorm (fp32 in) -> fp32 out -----------------------------
__global__ __launch_bounds__(256) void k_rmsnorm_f32(
        const float* __restrict__ x, const float* __restrict__ w,
        float* __restrict__ out) {
    int row = blockIdx.x, t = threadIdx.x;
    const float4* xr = (const float4*)(x + (size_t)row * D_MODEL);
    float4 a = xr[t], b = xr[t + 256];
    float ss = a.x*a.x + a.y*a.y + a.z*a.z + a.w*a.w
             + b.x*b.x + b.y*b.y + b.z*b.z + b.w*b.w;
    for (int m = 1; m < 64; m <<= 1) ss += __shfl_xor(ss, m);
    __shared__ float sred[4];
    if ((t & 63) == 0) sred[t >> 6] = ss;
    __syncthreads();
    float r = rsqrtf((sred[0] + sred[1] + sred[2] + sred[3]) * (1.0f / D_MODEL) + EPSV);
    const float4* wr = (const float4*)w;
    float4 wa = wr[t], wb = wr[t + 256];
    float4 oa, ob;
    oa.x = a.x * r * wa.x; oa.y = a.y * r * wa.y; oa.z = a.z * r * wa.z; oa.w = a.w * r * wa.w;
    ob.x = b.x * r * wb.x; ob.y = b.y * r * wb.y; ob.z = b.z * r * wb.z; ob.w = b.w * r * wb.w;
    float4* o = (float4*)(out + (size_t)row * D_MODEL);
    o[t] = oa; o[t + 256] = ob;
}

// -------- transpose + fp32->bf16: in [R][C] -> out [C][R] -------------------
__global__ __launch_bounds__(256) void k_transpose_cvt(
        const float* __restrict__ in, ushort_t* __restrict__ out, int R, int C) {
    __shared__ float tile[32][33];
    int bc = blockIdx.x * 32, br = blockIdx.y * 32;
    int t = threadIdx.x, lr = t >> 5, lc = t & 31;
    for (int i = 0; i < 4; i++)
        tile[lr + i * 8][lc] = in[(size_t)(br + lr + i * 8) * C + bc + lc];
    __syncthreads();
    for (int i = 0; i < 4; i++)
        out[(size_t)(bc + lr + i * 8) * R + br + lc] = f2b(tile[lc][lr + i * 8]);
}

// -------- GEMM (m97 structure): C[M,N] = A[M,K](bf16)*Bt[N,K](bf16) ---------
// 128x128 tile, BK=32, global_load_lds width-16 staging, unpadded LDS.
// MODE 0: clip(+-8) -> bf16 out.  MODE 1: += resid -> fp32 out.
template <int MODE>
__global__ __launch_bounds__(256) void k_gemm(
        const ushort_t* __restrict__ A, const ushort_t* __restrict__ Bt,
        void* __restrict__ Cout, const float* __restrict__ resid,
        int M, int N, int K) {
    __shared__ __align__(16) ushort_t sA[128 * 32];
    __shared__ __align__(16) ushort_t sB[128 * 32];
    int bm = blockIdx.y * 128, bn = blockIdx.x * 128;
    int t = threadIdx.x;
    int wv = t >> 6, lane = t & 63;
    int wm = (wv >> 1) * 64, wn = (wv & 1) * 64;
    int q4 = lane >> 4, n16 = lane & 15;

    // staging: wave wv covers rows [wv*32, wv*32+32), two 16-row chunks
    int srow = lane >> 2, scol = (lane & 3) * 8;
    const ushort_t* gA0 = A  + (size_t)(bm + wv * 32 + srow) * K + scol;
    const ushort_t* gA1 = gA0 + (size_t)16 * K;
    const ushort_t* gB0 = Bt + (size_t)(bn + wv * 32 + srow) * K + scol;
    const ushort_t* gB1 = gB0 + (size_t)16 * K;
    ushort_t* lA0 = sA + wv * 1024;   // bytes: wv*2048
    ushort_t* lA1 = lA0 + 512;
    ushort_t* lB0 = sB + wv * 1024;
    ushort_t* lB1 = lB0 + 512;

    floatx4 zero4 = {0.0f, 0.0f, 0.0f, 0.0f};
    floatx4 acc[4][4];
    for (int i = 0; i < 4; i++)
        for (int j = 0; j < 4; j++) acc[i][j] = zero4;

    for (int k0 = 0; k0 < K; k0 += 32) {
        GLD_LDS16(gA0 + k0, lA0);
        GLD_LDS16(gA1 + k0, lA1);
        GLD_LDS16(gB0 + k0, lB0);
        GLD_LDS16(gB1 + k0, lB1);
        __syncthreads();   // drains vmcnt: staging visible to all
        short8 af[4], bfr[4];
        for (int i = 0; i < 4; i++) af[i]  = *(const short8*)&sA[(wm + i * 16 + n16) * 32 + q4 * 8];
        for (int j = 0; j < 4; j++) bfr[j] = *(const short8*)&sB[(wn + j * 16 + n16) * 32 + q4 * 8];
        for (int i = 0; i < 4; i++)
            for (int j = 0; j < 4; j++)
                acc[i][j] = __builtin_amdgcn_mfma_f32_16x16x32_bf16(af[i], bfr[j], acc[i][j], 0, 0, 0);
        __syncthreads();   // all ds_reads done before next stage overwrites
    }

    for (int i = 0; i < 4; i++) {
        int rbase = bm + wm + i * 16 + q4 * 4;
        for (int j = 0; j < 4; j++) {
            int col = bn + wn + j * 16 + n16;
            if (MODE == 0) {
                ushort_t* C = (ushort_t*)Cout;
                for (int r = 0; r < 4; r++) {
                    float v = acc[i][j][r];
                    v = fminf(fmaxf(v, -8.0f), 8.0f);
                    C[(size_t)(rbase + r) * N + col] = f2b(v);
                }
            } else {
                float* C = (float*)Cout;
                for (int r = 0; r < 4; r++) {
                    float v = acc[i][j][r] + resid[(size_t)(rbase + r) * N + col];
                    C[(size_t)(rbase + r) * N + col] = v;
                }
            }
        }
    }
}

// -------- RoPE + scatter; Q pre-scaled by 1/sqrt(d)*log2e -------------------
__global__ __launch_bounds__(256) void k_rope(
        const ushort_t* __restrict__ qkv, const int* __restrict__ pos_ids,
        const float* __restrict__ rsin, const float* __restrict__ rcos,
        ushort_t* __restrict__ qout, ushort_t* __restrict__ kout) {
    int wid  = blockIdx.x * 4 + (threadIdx.x >> 6);
    int lane = threadIdx.x & 63;
    int row = wid / 20, slot = wid - row * 20;   // 16 q slots + 4 k slots
    int b = row >> 11, s = row & 2047;
    int pos = pos_ids[row];
    int col0 = (slot < 16) ? slot * HD : D_MODEL + (slot - 16) * HD;
    const ushort_t* src = qkv + (size_t)row * QKV_N + col0;
    float xl = b2f(src[lane]);
    float xh = b2f(src[lane + 64]);
    const float* cp = rcos + (size_t)pos * HD;
    const float* sp = rsin + (size_t)pos * HD;
    float cl = cp[lane], sl = sp[lane];
    float ch = cp[lane + 64], sh = sp[lane + 64];
    float mul = (slot < 16) ? QPRE : 1.0f;
    float ol = (xl * cl - xh * sl) * mul;
    float oh = (xh * ch + xl * sh) * mul;
    if (slot < 16) {
        size_t dst = ((size_t)(b * NH + slot) * SEQ + s) * HD;
        qout[dst + lane] = f2b(ol); qout[dst + lane + 64] = f2b(oh);
    } else {
        size_t dst = ((size_t)(b * NKV + (slot - 16)) * SEQ + s) * HD;
        kout[dst + lane] = f2b(ol); kout[dst + lane + 64] = f2b(oh);
    }
}

// -------- V transpose: qkv v-slot -> vt [NB,NKV,HD,SEQ] ---------------------
__global__ __launch_bounds__(256) void k_vtrans(
        const ushort_t* __restrict__ qkv, ushort_t* __restrict__ vt) {
    __shared__ ushort_t tile[32][33];
    int bh = blockIdx.z;                 // b*NKV + h
    int b = bh >> 2, h = bh & 3;
    int s0 = blockIdx.x * 32, d0 = blockIdx.y * 32;
    int t = threadIdx.x, lr = t >> 5, lc = t & 31;
    int col0 = D_MODEL + NKV * HD + h * HD;      // 2560 + h*128
    for (int i = 0; i < 4; i++)
        tile[lr + i * 8][lc] =
            qkv[((size_t)b * SEQ + s0 + lr + i * 8) * QKV_N + col0 + d0 + lc];
    __syncthreads();
    for (int i = 0; i < 4; i++)
        vt[((size_t)bh * HD + d0 + lr + i * 8) * SEQ + s0 + lc] = tile[lc][lr + i * 8];
}

// -------- MFMA flash attention v3: S^T formulation, zero-LDS ----------------
// Per wave: 32 q cols x 64 kv rows per iter. S^T = K·Q^T so P^T C-regs feed
// PV (16x16x16) B-operand directly (kv = q4*4+r matches B k-map). Scores in
// log2 domain (Q pre-scaled). Causal mask only in single peeled tail iter.
__global__ __launch_bounds__(256, 2) void k_attn(
        const ushort_t* __restrict__ Q, const ushort_t* __restrict__ Kr,
        const ushort_t* __restrict__ Vt, const int* __restrict__ amask,
        ushort_t* __restrict__ O) {
    int bidx = blockIdx.x;
    int qt = (SEQ / 128 - 1) - (bidx >> 5);   // LPT: long blocks first
    int bh = bidx & 31, h = bh & 15, b = bh >> 4;
    int wave = threadIdx.x >> 6, lane = threadIdx.x & 63;
    int q4 = lane >> 4, n16 = lane & 15;
    const ushort_t* Qh = Q  + (size_t)bh * SEQ * HD;
    const ushort_t* Kh = Kr + (size_t)(b * NKV + (h >> 2)) * SEQ * HD;
    const ushort_t* Vh = Vt + (size_t)(b * NKV + (h >> 2)) * HD * SEQ;
    const int* am = amask + b * SEQ;

    int q0 = qt * 128 + wave * 32;            // this wave's 32 q
    // Q as B-fragment (n = q): lane holds q-col q0+mm*16+n16, d = kk*32+q4*8+j
    short8 qf[2][4];
    for (int mm = 0; mm < 2; mm++)
        for (int kk = 0; kk < 4; kk++)
            qf[mm][kk] = *(const short8*)(Qh + (size_t)(q0 + mm * 16 + n16) * HD + kk * 32 + q4 * 8);

    floatx4 zero4 = {0.0f, 0.0f, 0.0f, 0.0f};
    floatx4 o_acc[2][8];                      // O^T[d][q]: rows d=dt*16+q4*4+r, col q
    for (int mm = 0; mm < 2; mm++)
        for (int dt = 0; dt < 8; dt++) o_acc[mm][dt] = zero4;
    float m_i[2] = {-INFINITY, -INFINITY};
    float l_i[2] = {0.0f, 0.0f};
    int qcol[2] = {q0 + n16, q0 + 16 + n16};

    int nm_end = q0 & ~63;                    // kv0 < nm_end: causal-free
    for (int kv0 = 0; kv0 <= nm_end; kv0 += 64) {
        bool tail = (kv0 == nm_end);          // wave-uniform
        // ---- S^T tiles: st[jj][mm], rows kv = kv0+jj*16+q4*4+r, col q ----
        floatx4 st[4][2];
        for (int jj = 0; jj < 4; jj++) { st[jj][0] = zero4; st[jj][1] = zero4; }
        for (int jj = 0; jj < 4; jj++) {
            const ushort_t* krow = Kh + (size_t)(kv0 + jj * 16 + n16) * HD + q4 * 8;
            for (int kk = 0; kk < 4; kk++) {
                short8 kf = *(const short8*)(krow + kk * 32);
                st[jj][0] = __builtin_amdgcn_mfma_f32_16x16x32_bf16(kf, qf[0][kk], st[jj][0], 0, 0, 0);
                st[jj][1] = __builtin_amdgcn_mfma_f32_16x16x32_bf16(kf, qf[1][kk], st[jj][1], 0, 0, 0);
            }
        }
        // ---- masking (to -1e30 in log2 domain, before rowmax) ----
        for (int jj = 0; jj < 4; jj++) {
            int kvb = kv0 + jj * 16 + q4 * 4;
            int4 am4 = *(const int4*)(am + kvb);
            int amr[4] = {am4.x, am4.y, am4.z, am4.w};
            if (tail) {
                for (int r = 0; r < 4; r++) {
                    bool av = amr[r] > 0;
                    int kv = kvb + r;
                    st[jj][0][r] = (av && kv <= qcol[0]) ? st[jj][0][r] : -1e30f;
                    st[jj][1][r] = (av && kv <= qcol[1]) ? st[jj][1][r] : -1e30f;
                }
            } else {
                for (int r = 0; r < 4; r++) {
                    bool av = amr[r] > 0;
                    st[jj][0][r] = av ? st[jj][0][r] : -1e30f;
                    st[jj][1][r] = av ? st[jj][1][r] : -1e30f;
                }
            }
        }
        // ---- online softmax along kv (regs + q4 groups) ----
        float al[2];
        for (int mm = 0; mm < 2; mm++) {
            float mx = st[0][mm][0];
            for (int jj = 0; jj < 4; jj++)
                for (int r = 0; r < 4; r++) mx = fmaxf(mx, st[jj][mm][r]);
            mx = fmaxf(mx, __shfl_xor(mx, 16));
            mx = fmaxf(mx, __shfl_xor(mx, 32));
            float mnew = fmaxf(m_i[mm], mx);
            al[mm] = exp2f(m_i[mm] - mnew);
            m_i[mm] = mnew;
            float rs = 0.0f;
            for (int jj = 0; jj < 4; jj++)
                for (int r = 0; r < 4; r++) {
                    float p = exp2f(st[jj][mm][r] - mnew);
                    st[jj][mm][r] = p;
                    rs += p;
                }
            rs += __shfl_xor(rs, 16);
            rs += __shfl_xor(rs, 32);
            l_i[mm] = l_i[mm] * al[mm] + rs;
        }
        for (int mm = 0; mm < 2; mm++)
            for (int dt = 0; dt < 8; dt++)
                o_acc[mm][dt] *= al[mm];
        // ---- PV: P^T B-frags straight from st regs; V^T A-frags 8B loads ----
        for (int jj = 0; jj < 4; jj++) {
            short4v pfr[2];
            for (int mm = 0; mm < 2; mm++) {
                union { unsigned u[2]; short4v s; } uu;
                uu.u[0] = pkbf(st[jj][mm][0], st[jj][mm][1]);
                uu.u[1] = pkbf(st[jj][mm][2], st[jj][mm][3]);
                pfr[mm] = uu.s;
            }
            const ushort_t* vbase = Vh + kv0 + jj * 16 + q4 * 4;
            for (int dt = 0; dt < 8; dt++) {
                short4v vf = *(const short4v*)(vbase + (size_t)(dt * 16 + n16) * SEQ);
                o_acc[0][dt] = pv_mfma(vf, pfr[0], o_acc[0][dt]);
                o_acc[1][dt] = pv_mfma(vf, pfr[1], o_acc[1][dt]);
            }
        }
    }
    // ---- epilogue: divide by l, pack pairs, 8B stores ----
    for (int mm = 0; mm < 2; mm++) {
        float inv = 1.0f / l_i[mm];
        ushort_t* orow = O + ((size_t)(b * SEQ) + qcol[mm]) * D_MODEL + h * HD + q4 * 4;
        for (int dt = 0; dt < 8; dt++) {
            unsigned lo = pkbf(o_acc[mm][dt][0] * inv, o_acc[mm][dt][1] * inv);
            unsigned hi = pkbf(o_acc[mm][dt][2] * inv, o_acc[mm][dt][3] * inv);
            uint2 pk; pk.x = lo; pk.y = hi;
            *(uint2*)(orow + dt * 16) = pk;
        }
    }
}

// ---------------------------------------------------------------------------
extern "C" void kernel_launch(void* const* d_in, const int* in_sizes, int n_in,
                              void* d_out, int out_size, void* d_ws, size_t ws_size,
                              hipStream_t stream) {
    const float* hidden = (const float*)d_in[0];
    const int*   amask  = (const int*)d_in[1];
    const int*   pos    = (const int*)d_in[2];
    const float* wqkv   = (const float*)d_in[3];
    const float* wout   = (const float*)d_in[4];
    const float* n1w    = (const float*)d_in[5];
    const float* n2w    = (const float*)d_in[6];
    const float* rsin   = (const float*)d_in[7];
    const float* rcos   = (const float*)d_in[8];
    float* out0 = (float*)d_out;
    float* out1 = out0 + (size_t)ROWS * D_MODEL;

    char* ws = (char*)d_ws;
    ushort_t* x_bf    = (ushort_t*)ws;  ws += (size_t)ROWS * D_MODEL * 2;
    ushort_t* wqkv_t  = (ushort_t*)ws;  ws += (size_t)QKV_N * D_MODEL * 2;
    ushort_t* wout_t  = (ushort_t*)ws;  ws += (size_t)D_MODEL * D_MODEL * 2;
    ushort_t* qkv     = (ushort_t*)ws;  ws += (size_t)ROWS * QKV_N * 2;
    ushort_t* qrot    = (ushort_t*)ws;  ws += (size_t)NB * NH * SEQ * HD * 2;
    ushort_t* krot    = (ushort_t*)ws;  ws += (size_t)NB * NKV * SEQ * HD * 2;
    ushort_t* vt      = (ushort_t*)ws;  ws += (size_t)NB * NKV * HD * SEQ * 2;
    ushort_t* attn    = (ushort_t*)ws;  ws += (size_t)ROWS * D_MODEL * 2;

    k_rmsnorm_bf16<<<ROWS, 256, 0, stream>>>(hidden, n1w, x_bf);
    k_transpose_cvt<<<dim3(QKV_N / 32, D_MODEL / 32), 256, 0, stream>>>(wqkv, wqkv_t, D_MODEL, QKV_N);
    k_transpose_cvt<<<dim3(D_MODEL / 32, D_MODEL / 32), 256, 0, stream>>>(wout, wout_t, D_MODEL, D_MODEL);
    k_gemm<0><<<dim3(QKV_N / 128, ROWS / 128), 256, 0, stream>>>(x_bf, wqkv_t, qkv, nullptr, ROWS, QKV_N, D_MODEL);
    k_rope<<<ROWS * 20 / 4, 256, 0, stream>>>(qkv, pos, rsin, rcos, qrot, krot);
    k_vtrans<<<dim3(SEQ / 32, HD / 32, NB * NKV), 256, 0, stream>>>(qkv, vt);
    k_attn<<<(SEQ / 128) * 32, 256, 0, stream>>>(qrot, krot, vt, amask, attn);
    k_gemm<1><<<dim3(D_MODEL / 128, ROWS / 128), 256, 0, stream>>>(attn, wout_t, out0, hidden, ROWS, D_MODEL, D_MODEL);
    k_rmsnorm_f32<<<ROWS, 256, 0, stream>>>(out0, n2w, out1);
}

// Round 4
// 391.537 us; speedup vs baseline: 1.5516x; 1.5516x over previous
//
#include <hip/hip_runtime.h>
#include <cstdint>
#include <cstddef>

#define D_MODEL 2048
#define SEQ     2048
#define NB      2
#define ROWS    4096      // NB*SEQ
#define QKV_N   3072      // 2048 + 2*4*128
#define NH      16
#define NKV     4
#define HD      128
#define EPSV    1e-5f
// 1/sqrt(128) * log2(e): folded into Q at RoPE time -> scores arrive in log2 domain
#define QPRE    (0.08838834764831845f * 1.4426950408889634f)

typedef unsigned short ushort_t;
typedef __attribute__((ext_vector_type(8))) short  short8;
typedef __attribute__((ext_vector_type(4))) short  short4v;
typedef __attribute__((ext_vector_type(4))) float  floatx4;

__device__ __forceinline__ ushort_t f2b(float f) {
    unsigned u = __float_as_uint(f);
    u += 0x7fffu + ((u >> 16) & 1u);   // RNE bf16
    return (ushort_t)(u >> 16);
}
__device__ __forceinline__ float b2f(ushort_t u) {
    return __uint_as_float(((unsigned)u) << 16);
}

// pack two f32 -> bf16 pair
__device__ __forceinline__ unsigned pkbf(float lo, float hi) {
    unsigned u0 = __float_as_uint(lo) + 0x8000u;
    unsigned u1 = __float_as_uint(hi) + 0x8000u;
    return __builtin_amdgcn_perm(u1, u0, 0x07060302u);
}

#if __has_builtin(__builtin_amdgcn_mfma_f32_16x16x16bf16_1k)
#define HAVE_1K 1
#endif

__device__ __forceinline__ floatx4 pv_mfma(short4v a, short4v b, floatx4 c) {
#ifdef HAVE_1K
    return __builtin_amdgcn_mfma_f32_16x16x16bf16_1k(a, b, c, 0, 0, 0);
#else
    short8 a8 = {a[0], a[1], a[2], a[3], 0, 0, 0, 0};
    short8 b8 = {b[0], b[1], b[2], b[3], 0, 0, 0, 0};
    return __builtin_amdgcn_mfma_f32_16x16x32_bf16(a8, b8, c, 0, 0, 0);
#endif
}

#define GLD_LDS16(gp, lp) __builtin_amdgcn_global_load_lds( \
    (const __attribute__((address_space(1))) void*)(gp),   \
    (__attribute__((address_space(3))) void*)(lp), 16, 0, 0)

// ---------------- RMSNorm (fp32 in) -> bf16 out -----------------------------
__global__ __launch_bounds__(256) void k_rmsnorm_bf16(
        const float* __restrict__ x, const float* __restrict__ w,
        ushort_t* __restrict__ out) {
    int row = blockIdx.x, t = threadIdx.x;
    const float4* xr = (const float4*)(x + (size_t)row * D_MODEL);
    float4 a = xr[t], b = xr[t + 256];
    float ss = a.x*a.x + a.y*a.y + a.z*a.z + a.w*a.w
             + b.x*b.x + b.y*b.y + b.z*b.z + b.w*b.w;
    for (int m = 1; m < 64; m <<= 1) ss += __shfl_xor(ss, m);
    __shared__ float sred[4];
    if ((t & 63) == 0) sred[t >> 6] = ss;
    __syncthreads();
    float r = rsqrtf((sred[0] + sred[1] + sred[2] + sred[3]) * (1.0f / D_MODEL) + EPSV);
    const float4* wr = (const float4*)w;
    float4 wa = wr[t], wb = wr[t + 256];
    ushort4 pa, pb;
    pa.x = f2b(a.x * r * wa.x); pa.y = f2b(a.y * r * wa.y);
    pa.z = f2b(a.z * r * wa.z); pa.w = f2b(a.w * r * wa.w);
    pb.x = f2b(b.x * r * wb.x); pb.y = f2b(b.y * r * wb.y);
    pb.z = f2b(b.z * r * wb.z); pb.w = f2b(b.w * r * wb.w);
    ushort4* o = (ushort4*)(out + (size_t)row * D_MODEL);
    o[t] = pa; o[t + 256] = pb;
}

// ---------------- RMSNorm (fp32 in) -> fp32 out -----------------------------
__global__ __launch_bounds__(256) void k_rmsnorm_f32(
        const float* __restrict__ x, const float* __restrict__ w,
        float* __restrict__ out) {
    int row = blockIdx.x, t = threadIdx.x;
    const float4* xr = (const float4*)(x + (size_t)row * D_MODEL);
    float4 a = xr[t], b = xr[t + 256];
    float ss = a.x*a.x + a.y*a.y + a.z*a.z + a.w*a.w
             + b.x*b.x + b.y*b.y + b.z*b.z + b.w*b.w;
    for (int m = 1; m < 64; m <<= 1) ss += __shfl_xor(ss, m);
    __shared__ float sred[4];
    if ((t & 63) == 0) sred[t >> 6] = ss;
    __syncthreads();
    float r = rsqrtf((sred[0] + sred[1] + sred[2] + sred[3]) * (1.0f / D_MODEL) + EPSV);
    const float4* wr = (const float4*)w;
    float4 wa = wr[t], wb = wr[t + 256];
    float4 oa, ob;
    oa.x = a.x * r * wa.x; oa.y = a.y * r * wa.y; oa.z = a.z * r * wa.z; oa.w = a.w * r * wa.w;
    ob.x = b.x * r * wb.x; ob.y = b.y * r * wb.y; ob.z = b.z * r * wb.z; ob.w = b.w * r * wb.w;
    float4* o = (float4*)(out + (size_t)row * D_MODEL);
    o[t] = oa; o[t + 256] = ob;
}

// -------- transpose + fp32->bf16: in [R][C] -> out [C][R] -------------------
__global__ __launch_bounds__(256) void k_transpose_cvt(
        const float* __restrict__ in, ushort_t* __restrict__ out, int R, int C) {
    __shared__ float tile[32][33];
    int bc = blockIdx.x * 32, br = blockIdx.y * 32;
    int t = threadIdx.x, lr = t >> 5, lc = t & 31;
    for (int i = 0; i < 4; i++)
        tile[lr + i * 8][lc] = in[(size_t)(br + lr + i * 8) * C + bc + lc];
    __syncthreads();
    for (int i = 0; i < 4; i++)
        out[(size_t)(bc + lr + i * 8) * R + br + lc] = f2b(tile[lc][lr + i * 8]);
}

// -------- GEMM (m97 structure): C[M,N] = A[M,K](bf16)*Bt[N,K](bf16) ---------
template <int MODE>
__global__ __launch_bounds__(256) void k_gemm(
        const ushort_t* __restrict__ A, const ushort_t* __restrict__ Bt,
        void* __restrict__ Cout, const float* __restrict__ resid,
        int M, int N, int K) {
    __shared__ __align__(16) ushort_t sA[128 * 32];
    __shared__ __align__(16) ushort_t sB[128 * 32];
    int bm = blockIdx.y * 128, bn = blockIdx.x * 128;
    int t = threadIdx.x;
    int wv = t >> 6, lane = t & 63;
    int wm = (wv >> 1) * 64, wn = (wv & 1) * 64;
    int q4 = lane >> 4, n16 = lane & 15;

    int srow = lane >> 2, scol = (lane & 3) * 8;
    const ushort_t* gA0 = A  + (size_t)(bm + wv * 32 + srow) * K + scol;
    const ushort_t* gA1 = gA0 + (size_t)16 * K;
    const ushort_t* gB0 = Bt + (size_t)(bn + wv * 32 + srow) * K + scol;
    const ushort_t* gB1 = gB0 + (size_t)16 * K;
    ushort_t* lA0 = sA + wv * 1024;
    ushort_t* lA1 = lA0 + 512;
    ushort_t* lB0 = sB + wv * 1024;
    ushort_t* lB1 = lB0 + 512;

    floatx4 zero4 = {0.0f, 0.0f, 0.0f, 0.0f};
    floatx4 acc[4][4];
    for (int i = 0; i < 4; i++)
        for (int j = 0; j < 4; j++) acc[i][j] = zero4;

    for (int k0 = 0; k0 < K; k0 += 32) {
        GLD_LDS16(gA0 + k0, lA0);
        GLD_LDS16(gA1 + k0, lA1);
        GLD_LDS16(gB0 + k0, lB0);
        GLD_LDS16(gB1 + k0, lB1);
        __syncthreads();
        short8 af[4], bfr[4];
        for (int i = 0; i < 4; i++) af[i]  = *(const short8*)&sA[(wm + i * 16 + n16) * 32 + q4 * 8];
        for (int j = 0; j < 4; j++) bfr[j] = *(const short8*)&sB[(wn + j * 16 + n16) * 32 + q4 * 8];
        for (int i = 0; i < 4; i++)
            for (int j = 0; j < 4; j++)
                acc[i][j] = __builtin_amdgcn_mfma_f32_16x16x32_bf16(af[i], bfr[j], acc[i][j], 0, 0, 0);
        __syncthreads();
    }

    for (int i = 0; i < 4; i++) {
        int rbase = bm + wm + i * 16 + q4 * 4;
        for (int j = 0; j < 4; j++) {
            int col = bn + wn + j * 16 + n16;
            if (MODE == 0) {
                ushort_t* C = (ushort_t*)Cout;
                for (int r = 0; r < 4; r++) {
                    float v = acc[i][j][r];
                    v = fminf(fmaxf(v, -8.0f), 8.0f);
                    C[(size_t)(rbase + r) * N + col] = f2b(v);
                }
            } else {
                float* C = (float*)Cout;
                for (int r = 0; r < 4; r++) {
                    float v = acc[i][j][r] + resid[(size_t)(rbase + r) * N + col];
                    C[(size_t)(rbase + r) * N + col] = v;
                }
            }
        }
    }
}

// -------- RoPE + scatter; Q pre-scaled by 1/sqrt(d)*log2e -------------------
__global__ __launch_bounds__(256) void k_rope(
        const ushort_t* __restrict__ qkv, const int* __restrict__ pos_ids,
        const float* __restrict__ rsin, const float* __restrict__ rcos,
        ushort_t* __restrict__ qout, ushort_t* __restrict__ kout) {
    int wid  = blockIdx.x * 4 + (threadIdx.x >> 6);
    int lane = threadIdx.x & 63;
    int row = wid / 20, slot = wid - row * 20;
    int b = row >> 11, s = row & 2047;
    int pos = pos_ids[row];
    int col0 = (slot < 16) ? slot * HD : D_MODEL + (slot - 16) * HD;
    const ushort_t* src = qkv + (size_t)row * QKV_N + col0;
    float xl = b2f(src[lane]);
    float xh = b2f(src[lane + 64]);
    const float* cp = rcos + (size_t)pos * HD;
    const float* sp = rsin + (size_t)pos * HD;
    float cl = cp[lane], sl = sp[lane];
    float ch = cp[lane + 64], sh = sp[lane + 64];
    float mul = (slot < 16) ? QPRE : 1.0f;
    float ol = (xl * cl - xh * sl) * mul;
    float oh = (xh * ch + xl * sh) * mul;
    if (slot < 16) {
        size_t dst = ((size_t)(b * NH + slot) * SEQ + s) * HD;
        qout[dst + lane] = f2b(ol); qout[dst + lane + 64] = f2b(oh);
    } else {
        size_t dst = ((size_t)(b * NKV + (slot - 16)) * SEQ + s) * HD;
        kout[dst + lane] = f2b(ol); kout[dst + lane + 64] = f2b(oh);
    }
}

// -------- V transpose: qkv v-slot -> vt [NB,NKV,HD,SEQ] ---------------------
__global__ __launch_bounds__(256) void k_vtrans(
        const ushort_t* __restrict__ qkv, ushort_t* __restrict__ vt) {
    __shared__ ushort_t tile[32][33];
    int bh = blockIdx.z;
    int b = bh >> 2, h = bh & 3;
    int s0 = blockIdx.x * 32, d0 = blockIdx.y * 32;
    int t = threadIdx.x, lr = t >> 5, lc = t & 31;
    int col0 = D_MODEL + NKV * HD + h * HD;
    for (int i = 0; i < 4; i++)
        tile[lr + i * 8][lc] =
            qkv[((size_t)b * SEQ + s0 + lr + i * 8) * QKV_N + col0 + d0 + lc];
    __syncthreads();
    for (int i = 0; i < 4; i++)
        vt[((size_t)bh * HD + d0 + lr + i * 8) * SEQ + s0 + lc] = tile[lc][lr + i * 8];
}

// -------- MFMA flash attention v4: block-coop LDS staging, S^T regs ---------
// Block: 4 waves x 16q = 64 q. Grid: 32 qt x 32 bh = 1024 blocks (LPT desc).
// Per iter (64 kv): stage K[64][128] + Vt[128][64] into swizzled LDS via
// global_load_lds w16; QK^T as S^T (A=K from LDS, B=Q regs); softmax in regs
// (kv = q4*4+r -> per-lane scalar m/l, 2 shuffles); PV via 16x16x16 with P^T
// B-frags straight from C-regs, A=V^T from LDS.
__global__ __launch_bounds__(256, 4) void k_attn(
        const ushort_t* __restrict__ Q, const ushort_t* __restrict__ Kr,
        const ushort_t* __restrict__ Vt, const int* __restrict__ amask,
        ushort_t* __restrict__ O) {
    int bidx = blockIdx.x;
    int qt = (SEQ / 64 - 1) - (bidx >> 5);    // LPT: long blocks first
    int bh = bidx & 31, h = bh & 15, b = bh >> 4;
    int wave = threadIdx.x >> 6, lane = threadIdx.x & 63;
    int q4 = lane >> 4, n16 = lane & 15;

    __shared__ __align__(16) ushort_t sK[64 * 128];   // [kv][d], 16B chunks xor-swizzled
    __shared__ __align__(16) ushort_t sV[128 * 64];   // [d][kv], 16B chunks xor-swizzled

    const ushort_t* Qh = Q  + (size_t)bh * SEQ * HD;
    const ushort_t* Kh = Kr + (size_t)(b * NKV + (h >> 2)) * SEQ * HD;
    const ushort_t* Vh = Vt + (size_t)(b * NKV + (h >> 2)) * HD * SEQ;
    const int* am = amask + b * SEQ;

    int q0 = qt * 64 + wave * 16;             // this wave's 16 q cols
    int qcol = q0 + n16;

    short8 qf[4];                              // Q as B-frag: d = kk*32+q4*8+j
    for (int kk = 0; kk < 4; kk++)
        qf[kk] = *(const short8*)(Qh + (size_t)qcol * HD + kk * 32 + q4 * 8);

    floatx4 zero4 = {0.0f, 0.0f, 0.0f, 0.0f};
    floatx4 o_acc[8];                          // O^T[d][q]: d = dt*16+q4*4+r, col q=n16
    for (int dt = 0; dt < 8; dt++) o_acc[dt] = zero4;
    float m_i = -INFINITY, l_i = 0.0f;

    // staging lane geometry (computed once)
    int krow_l = (lane >> 4);                  // + wave*16 + t*4
    int kc_l   = lane & 15;
    int vrow_l = (lane >> 3);                  // + wave*32 + t*8
    int vc_l   = lane & 7;

    int kv_iters = qt + 1;
    for (int it = 0; it < kv_iters; it++) {
        int kv0 = it * 64;
        __syncthreads();                       // prior iter's LDS reads done
        #pragma unroll
        for (int t = 0; t < 4; t++) {
            int krow = wave * 16 + t * 4 + krow_l;
            int kc   = kc_l ^ (krow & 7);
            GLD_LDS16(Kh + (size_t)(kv0 + krow) * HD + kc * 8,
                      sK + (wave * 16 + t * 4) * 128);
            int vrow = wave * 32 + t * 8 + vrow_l;
            int vc   = vc_l ^ (vrow & 7);
            GLD_LDS16(Vh + (size_t)vrow * SEQ + kv0 + vc * 8,
                      sV + (wave * 32 + t * 8) * 64);
        }
        __syncthreads();                       // staging visible (vmcnt drained)

        bool tail = (kv0 + 63 > q0);           // wave-uniform causal-mask need
        // ---- S^T = K·Q^T: rows kv = q4*4+r (+jj*16), col q = n16 ----
        floatx4 st[4];
        for (int jj = 0; jj < 4; jj++) st[jj] = zero4;
        for (int jj = 0; jj < 4; jj++) {
            int krow = jj * 16 + n16;
            int sw = krow & 7;
            const ushort_t* kb = sK + krow * 128;
            for (int kk = 0; kk < 4; kk++) {
                short8 kf = *(const short8*)(kb + ((kk * 4 + q4) ^ sw) * 8);
                st[jj] = __builtin_amdgcn_mfma_f32_16x16x32_bf16(kf, qf[kk], st[jj], 0, 0, 0);
            }
        }
        // ---- mask ----
        for (int jj = 0; jj < 4; jj++) {
            int kvb = kv0 + jj * 16 + q4 * 4;
            int4 am4 = *(const int4*)(am + kvb);
            int amr[4] = {am4.x, am4.y, am4.z, am4.w};
            if (tail) {
                for (int r = 0; r < 4; r++)
                    st[jj][r] = (amr[r] > 0 && kvb + r <= qcol) ? st[jj][r] : -1e30f;
            } else {
                for (int r = 0; r < 4; r++)
                    st[jj][r] = (amr[r] > 0) ? st[jj][r] : -1e30f;
            }
        }
        // ---- online softmax (kv in regs + q4 groups: 2 shuffles per reduce) ----
        float mx = st[0][0];
        for (int jj = 0; jj < 4; jj++)
            for (int r = 0; r < 4; r++) mx = fmaxf(mx, st[jj][r]);
        mx = fmaxf(mx, __shfl_xor(mx, 16));
        mx = fmaxf(mx, __shfl_xor(mx, 32));
        float mnew = fmaxf(m_i, mx);
        float al = exp2f(m_i - mnew);
        m_i = mnew;
        float rs = 0.0f;
        for (int jj = 0; jj < 4; jj++)
            for (int r = 0; r < 4; r++) {
                float p = exp2f(st[jj][r] - mnew);
                st[jj][r] = p;
                rs += p;
            }
        rs += __shfl_xor(rs, 16);
        rs += __shfl_xor(rs, 32);
        l_i = l_i * al + rs;
        for (int dt = 0; dt < 8; dt++)
            o_acc[dt] *= al;
        // ---- PV: A = V^T frags from LDS (8B), B = P^T from st regs ----
        for (int jj = 0; jj < 4; jj++) {
            union { unsigned u[2]; short4v s; } uu;
            uu.u[0] = pkbf(st[jj][0], st[jj][1]);
            uu.u[1] = pkbf(st[jj][2], st[jj][3]);
            short4v pfr = uu.s;
            int ch = jj * 2 + (q4 >> 1), hh = q4 & 1;
            for (int dt = 0; dt < 8; dt++) {
                int vrow = dt * 16 + n16;
                short4v vf = *(const short4v*)(sV + vrow * 64 + ((ch ^ (vrow & 7)) * 8) + hh * 4);
                o_acc[dt] = pv_mfma(vf, pfr, o_acc[dt]);
            }
        }
    }
    // ---- epilogue: O^T lane holds d = dt*16+q4*4+r for col q = n16 ----
    float inv = 1.0f / l_i;
    ushort_t* orow = O + ((size_t)(b * SEQ) + qcol) * D_MODEL + h * HD + q4 * 4;
    for (int dt = 0; dt < 8; dt++) {
        uint2 pk;
        pk.x = pkbf(o_acc[dt][0] * inv, o_acc[dt][1] * inv);
        pk.y = pkbf(o_acc[dt][2] * inv, o_acc[dt][3] * inv);
        *(uint2*)(orow + dt * 16) = pk;
    }
}

// ---------------------------------------------------------------------------
extern "C" void kernel_launch(void* const* d_in, const int* in_sizes, int n_in,
                              void* d_out, int out_size, void* d_ws, size_t ws_size,
                              hipStream_t stream) {
    const float* hidden = (const float*)d_in[0];
    const int*   amask  = (const int*)d_in[1];
    const int*   pos    = (const int*)d_in[2];
    const float* wqkv   = (const float*)d_in[3];
    const float* wout   = (const float*)d_in[4];
    const float* n1w    = (const float*)d_in[5];
    const float* n2w    = (const float*)d_in[6];
    const float* rsin   = (const float*)d_in[7];
    const float* rcos   = (const float*)d_in[8];
    float* out0 = (float*)d_out;
    float* out1 = out0 + (size_t)ROWS * D_MODEL;

    char* ws = (char*)d_ws;
    ushort_t* x_bf    = (ushort_t*)ws;  ws += (size_t)ROWS * D_MODEL * 2;
    ushort_t* wqkv_t  = (ushort_t*)ws;  ws += (size_t)QKV_N * D_MODEL * 2;
    ushort_t* wout_t  = (ushort_t*)ws;  ws += (size_t)D_MODEL * D_MODEL * 2;
    ushort_t* qkv     = (ushort_t*)ws;  ws += (size_t)ROWS * QKV_N * 2;
    ushort_t* qrot    = (ushort_t*)ws;  ws += (size_t)NB * NH * SEQ * HD * 2;
    ushort_t* krot    = (ushort_t*)ws;  ws += (size_t)NB * NKV * SEQ * HD * 2;
    ushort_t* vt      = (ushort_t*)ws;  ws += (size_t)NB * NKV * HD * SEQ * 2;
    ushort_t* attn    = (ushort_t*)ws;  ws += (size_t)ROWS * D_MODEL * 2;

    k_rmsnorm_bf16<<<ROWS, 256, 0, stream>>>(hidden, n1w, x_bf);
    k_transpose_cvt<<<dim3(QKV_N / 32, D_MODEL / 32), 256, 0, stream>>>(wqkv, wqkv_t, D_MODEL, QKV_N);
    k_transpose_cvt<<<dim3(D_MODEL / 32, D_MODEL / 32), 256, 0, stream>>>(wout, wout_t, D_MODEL, D_MODEL);
    k_gemm<0><<<dim3(QKV_N / 128, ROWS / 128), 256, 0, stream>>>(x_bf, wqkv_t, qkv, nullptr, ROWS, QKV_N, D_MODEL);
    k_rope<<<ROWS * 20 / 4, 256, 0, stream>>>(qkv, pos, rsin, rcos, qrot, krot);
    k_vtrans<<<dim3(SEQ / 32, HD / 32, NB * NKV), 256, 0, stream>>>(qkv, vt);
    k_attn<<<(SEQ / 64) * 32, 256, 0, stream>>>(qrot, krot, vt, amask, attn);
    k_gemm<1><<<dim3(D_MODEL / 128, ROWS / 128), 256, 0, stream>>>(attn, wout_t, out0, hidden, ROWS, D_MODEL, D_MODEL);
    k_rmsnorm_f32<<<ROWS, 256, 0, stream>>>(out0, n2w, out1);
}